// Round 6
// baseline (297.767 us; speedup 1.0000x reference)
//
#include <hip/hip_runtime.h>
#include <hip/hip_cooperative_groups.h>
#include <math.h>

namespace cg = cooperative_groups;

#define KOBJ 512
#define KTW 12      // packed row: x[8], xk2, w_rep, w_att, pad
#define TK 64       // k-tile per pairs item
#define NTILE (KOBJ / TK)   // 8
#define HB 4        // hits per thread (register blocking)
#define HCH (256 * HB)      // 1024 hits per item
#define MPREP 512   // prep blocks (divisible by 32 for gather chunking)
#define GGATH 64    // gather blocks
#define GRID 512    // cooperative grid: 2 blocks/CU guaranteed resident

__device__ __forceinline__ float wave_red_f(float v) {
  #pragma unroll
  for (int off = 32; off > 0; off >>= 1) v += __shfl_down(v, off, 64);
  return v;
}

// fast atanh(b)^2 + 1 ; b in (0, 0.96]
__device__ __forceinline__ float q_of_beta(float b) {
  float a = 0.5f * __logf((1.f + b) / (1.f - b));
  return fmaf(a, a, 1.f);
}

// ======================= phase 1: prep =======================
__device__ __forceinline__ void
phase_prep(const float* __restrict__ beta, const int* __restrict__ oid,
           const float* __restrict__ energy, const float* __restrict__ eph,
           const float* __restrict__ mom, const float* __restrict__ mph,
           const float* __restrict__ logits, const int* __restrict__ pid,
           unsigned long long* __restrict__ amax_part,
           unsigned* __restrict__ cnt_part, float* __restrict__ scal_part,
           int n, int bid, int tid,
           unsigned long long* lmax, unsigned* lcnt, float (*sred)[10]) {
  for (int t = tid; t < KOBJ; t += 256) { lmax[t] = 0ull; lcnt[t] = 0u; }
  __syncthreads();

  float e_t = 0.f, p_t = 0.f, pid_t = 0.f, noise_t = 0.f, ncnt = 0.f, mcnt = 0.f;
  for (int i = bid * 256 + tid; i < n; i += MPREP * 256) {
    float b = beta[i];
    int o = oid[i];
    if (o > 0) {
      float q = q_of_beta(b);
      // pack (q bits | ~i): max-q wins, ties -> smallest index (argmax semantics)
      unsigned long long key = ((unsigned long long)__float_as_uint(q) << 32)
                             | (unsigned long long)(unsigned)(~(unsigned)i);
      atomicMax(&lmax[o - 1], key);
      atomicAdd(&lcnt[o - 1], 1u);
      mcnt += 1.f;
      float de = energy[i] - eph[i];
      e_t = fmaf(de, de, e_t);
      float p0 = mom[3*i+0] - mph[3*i+0];
      float p1 = mom[3*i+1] - mph[3*i+1];
      float p2 = mom[3*i+2] - mph[3*i+2];
      p_t = fmaf(p0, p0, p_t); p_t = fmaf(p1, p1, p_t); p_t = fmaf(p2, p2, p_t);
      const float* lg = logits + 6*i;
      float l0=lg[0], l1=lg[1], l2=lg[2], l3=lg[3], l4=lg[4], l5=lg[5];
      float mx = fmaxf(fmaxf(fmaxf(l0,l1),fmaxf(l2,l3)), fmaxf(l4,l5));
      float s = __expf(l0-mx)+__expf(l1-mx)+__expf(l2-mx)
              + __expf(l3-mx)+__expf(l4-mx)+__expf(l5-mx);
      int pc = pid[i];
      float lp = (pc==0)?l0:(pc==1)?l1:(pc==2)?l2:(pc==3)?l3:(pc==4)?l4:l5;
      pid_t += mx + __logf(s) - lp;
    } else {
      noise_t += b;
      ncnt += 1.f;
    }
  }
  __syncthreads();

  for (int t = tid; t < KOBJ; t += 256) {
    amax_part[(size_t)bid * KOBJ + t] = lmax[t];
    cnt_part[(size_t)bid * KOBJ + t]  = lcnt[t];
  }

  float vals[6] = {e_t, p_t, pid_t, noise_t, ncnt, mcnt};
  #pragma unroll
  for (int j = 0; j < 6; j++) vals[j] = wave_red_f(vals[j]);
  int w = tid >> 6, l = tid & 63;
  if (l == 0) {
    #pragma unroll
    for (int j = 0; j < 6; j++) sred[w][j] = vals[j];
  }
  __syncthreads();
  if (tid == 0) {
    #pragma unroll
    for (int j = 0; j < 6; j++)
      scal_part[bid * 8 + j] = sred[0][j]+sred[1][j]+sred[2][j]+sred[3][j];
  }
}

// ======================= phase 2: gather =======================
__device__ __forceinline__ void
phase_gather(const float* __restrict__ x, const float* __restrict__ beta,
             const unsigned long long* __restrict__ amax_part,
             const unsigned* __restrict__ cnt_part,
             float* __restrict__ ktab, float* __restrict__ cow_part,
             int n, int bid, int tid,
             unsigned long long (*skey)[8], unsigned (*scnt2)[8]) {
  int o = tid & 7;          // object within block (8 per block)
  int chunk = tid >> 3;     // 0..31 m-chunk
  int k = bid * 8 + o;      // global object id - 1
  const int mpc = MPREP / 32;   // 16
  unsigned long long key = 0ull;
  unsigned cnt = 0u;
  for (int m = chunk * mpc; m < (chunk + 1) * mpc; m++) {
    unsigned long long km = amax_part[(size_t)m * KOBJ + k];
    key = (km > key) ? km : key;
    cnt += cnt_part[(size_t)m * KOBJ + k];
  }
  skey[chunk][o] = key;
  scnt2[chunk][o] = cnt;
  __syncthreads();

  if (chunk == 0) {   // lanes 0..7 of wave 0
    #pragma unroll 4
    for (int c = 1; c < 32; c++) {
      unsigned long long kc = skey[c][o];
      key = (kc > key) ? kc : key;
      cnt += scnt2[c][o];
    }
    unsigned idx = ~(unsigned)(key & 0xffffffffull);
    float q_k = __uint_as_float((unsigned)(key >> 32));
    const float4* xp = (const float4*)x;
    float4 xa = xp[2 * (size_t)idx];
    float4 xb = xp[2 * (size_t)idx + 1];
    float xv[8] = {xa.x, xa.y, xa.z, xa.w, xb.x, xb.y, xb.z, xb.w};
    float s2 = 0.f;
    #pragma unroll
    for (int c = 0; c < 8; c++) s2 = fmaf(xv[c], xv[c], s2);
    float* kt = ktab + (size_t)k * KTW;
    #pragma unroll
    for (int c = 0; c < 8; c++) kt[c] = xv[c];
    kt[8]  = s2;
    kt[9]  = q_k / ((float)(n - (int)cnt) + 1e-9f);   // w_rep
    kt[10] = q_k / ((float)cnt + 1e-9f);              // w_att
    kt[11] = 0.f;
    float cow = 1.f - beta[idx];
    #pragma unroll
    for (int off = 4; off > 0; off >>= 1) cow += __shfl_down(cow, off, 8);
    if (o == 0) cow_part[bid] = cow;
  }
}

// ======================= phase 3: pairs (hot) =======================
__device__ __forceinline__ void
phase_pairs(const float* __restrict__ x, const float* __restrict__ beta,
            const int* __restrict__ oid, const float* __restrict__ ktab,
            float* __restrict__ pairs_part, int n, int nitems,
            int bid, int tid, int gridn, float* skt, float (*sred)[10]) {
  float att = 0.f, rep = 0.f, nrep = 0.f;
  for (int it = bid; it < nitems; it += gridn) {
    const int tile0 = (it & (NTILE - 1)) * TK;
    const int hbase = (it / NTILE) * HCH;

    __syncthreads();
    for (int t = tid; t < TK * KTW; t += 256)
      skt[t] = ktab[(size_t)tile0 * KTW + t];
    __syncthreads();

    float yi[HB][8], b2[HB], qi[HB];
    int own[HB];
    const float4* xp = (const float4*)x;
    #pragma unroll
    for (int h = 0; h < HB; h++) {
      int i = hbase + h * 256 + tid;
      if (i < n) {
        float4 xa = xp[2 * (size_t)i];
        float4 xb = xp[2 * (size_t)i + 1];
        float xi[8] = {xa.x, xa.y, xa.z, xa.w, xb.x, xb.y, xb.z, xb.w};
        float s = 0.f;
        #pragma unroll
        for (int c = 0; c < 8; c++) {
          s = fmaf(xi[c], xi[c], s);
          yi[h][c] = -2.f * xi[c];
        }
        b2[h] = s;
        qi[h] = q_of_beta(beta[i]);
        own[h] = oid[i] - 1 - tile0;   // own object within tile (or out of range)
      } else {
        #pragma unroll
        for (int c = 0; c < 8; c++) yi[h][c] = 0.f;
        b2[h] = 3.f;                   // d2 = 3 + xk2 >= 3 : never passes hinge
        qi[h] = 0.f;
        own[h] = -1;
      }
    }

    #pragma unroll 2
    for (int k = 0; k < TK; k++) {
      const float* kt = &skt[k * KTW];
      float k0 = kt[0], k1 = kt[1], k2 = kt[2], k3 = kt[3];
      float k4 = kt[4], k5 = kt[5], k6 = kt[6], k7 = kt[7];
      float s2 = kt[8], wr = kt[9];
      #pragma unroll
      for (int h = 0; h < HB; h++) {
        float d2 = b2[h] + s2;
        d2 = fmaf(yi[h][0], k0, d2);
        d2 = fmaf(yi[h][1], k1, d2);
        d2 = fmaf(yi[h][2], k2, d2);
        d2 = fmaf(yi[h][3], k3, d2);
        d2 = fmaf(yi[h][4], k4, d2);
        d2 = fmaf(yi[h][5], k5, d2);
        d2 = fmaf(yi[h][6], k6, d2);
        d2 = fmaf(yi[h][7], k7, d2);
        // dist<1 <=> d2<1 ; sqrt only on the rare accepted pair
        if (d2 < 1.f) {
          float dist = sqrtf(fmaxf(d2, 1e-12f));
          rep = fmaf(qi[h] * (1.f - dist), wr, rep);
          nrep += 1.f;
        }
      }
    }

    // own-object: attractive term + undo in-loop repulsive contribution
    #pragma unroll
    for (int h = 0; h < HB; h++) {
      int ko = own[h];
      if (ko >= 0 && ko < TK) {
        const float* kt = &skt[ko * KTW];
        float d2 = b2[h] + kt[8];
        #pragma unroll
        for (int c = 0; c < 8; c++) d2 = fmaf(yi[h][c], kt[c], d2);
        att = fmaf(qi[h] * fmaxf(d2, 0.f), kt[10], att);
        if (d2 < 1.f) {
          float dist = sqrtf(fmaxf(d2, 1e-12f));
          rep = fmaf(-qi[h] * (1.f - dist), kt[9], rep);
          nrep -= 1.f;
        }
      }
    }
  }

  att = wave_red_f(att);
  rep = wave_red_f(rep);
  nrep = wave_red_f(nrep);
  __syncthreads();
  int w = tid >> 6, l = tid & 63;
  if (l == 0) { sred[w][0] = att; sred[w][1] = rep; sred[w][2] = nrep; }
  __syncthreads();
  if (tid == 0) {
    pairs_part[bid * 4 + 0] = sred[0][0]+sred[1][0]+sred[2][0]+sred[3][0];
    pairs_part[bid * 4 + 1] = sred[0][1]+sred[1][1]+sred[2][1]+sred[3][1];
    pairs_part[bid * 4 + 2] = sred[0][2]+sred[1][2]+sred[2][2]+sred[3][2];
  }
}

// ======================= phase 4: finalize =======================
__device__ __forceinline__ void
phase_final(const float* __restrict__ pairs_part, int nb_part,
            const float* __restrict__ scal_part,
            const float* __restrict__ cow_part, float* __restrict__ out,
            int tid, float (*sred)[10]) {
  float v[10];
  #pragma unroll
  for (int j = 0; j < 10; j++) v[j] = 0.f;
  // v: att, rep, nrep, e, p, pid, noise, ncnt, mcnt, cow
  for (int b = tid; b < nb_part; b += 256) {
    v[0] += pairs_part[b * 4 + 0];
    v[1] += pairs_part[b * 4 + 1];
    v[2] += pairs_part[b * 4 + 2];
  }
  for (int m = tid; m < MPREP; m += 256) {
    #pragma unroll
    for (int j = 0; j < 6; j++) v[3 + j] += scal_part[m * 8 + j];
  }
  for (int g = tid; g < GGATH; g += 256) v[9] += cow_part[g];
  #pragma unroll
  for (int j = 0; j < 10; j++) v[j] = wave_red_f(v[j]);
  __syncthreads();
  int w = tid >> 6, l = tid & 63;
  if (l == 0) {
    #pragma unroll
    for (int j = 0; j < 10; j++) sred[w][j] = v[j];
  }
  __syncthreads();
  if (tid == 0) {
    float t[10];
    #pragma unroll
    for (int j = 0; j < 10; j++) t[j] = sred[0][j]+sred[1][j]+sred[2][j]+sred[3][j];
    float v_att  = t[0] / (float)KOBJ;
    float v_rep  = t[1] / (float)KOBJ;
    float n_rep  = t[2];
    float l_cow  = t[9] / (float)KOBJ;
    float l_noise = t[6] / t[7];
    float oc = v_att + v_rep + l_cow + l_noise;
    float nm = t[8];
    float e_loss  = t[3] / nm;
    float p_loss  = t[4] / (nm * 3.f);
    float pid_loss = t[5] / nm;
    out[0] = v_att;
    out[1] = v_rep;
    out[2] = l_cow;
    out[3] = l_noise;
    out[4] = n_rep;
    out[5] = oc;
    out[6] = e_loss;
    out[7] = p_loss;
    out[8] = pid_loss;
    out[9] = oc + e_loss + p_loss + pid_loss;
  }
}

// ======================= fused cooperative kernel =======================
__global__ __launch_bounds__(256, 2) void
k_fused(const float* __restrict__ beta, const float* __restrict__ x,
        const int* __restrict__ oid,
        const float* __restrict__ energy, const float* __restrict__ eph,
        const float* __restrict__ mom, const float* __restrict__ mph,
        const float* __restrict__ logits, const int* __restrict__ pid,
        unsigned long long* __restrict__ amax_part,
        unsigned* __restrict__ cnt_part, float* __restrict__ scal_part,
        float* __restrict__ ktab, float* __restrict__ cow_part,
        float* __restrict__ pairs_part, float* __restrict__ out,
        int n, int nitems) {
  cg::grid_group grid = cg::this_grid();
  const int tid = threadIdx.x;
  const int bid = blockIdx.x;

  __shared__ unsigned long long lmax[KOBJ];
  __shared__ unsigned lcnt[KOBJ];
  __shared__ unsigned long long skey[32][8];
  __shared__ unsigned scnt2[32][8];
  __shared__ float skt[TK * KTW];
  __shared__ float sred[4][10];

  if (bid < MPREP)
    phase_prep(beta, oid, energy, eph, mom, mph, logits, pid,
               amax_part, cnt_part, scal_part, n, bid, tid, lmax, lcnt, sred);
  grid.sync();
  if (bid < GGATH)
    phase_gather(x, beta, amax_part, cnt_part, ktab, cow_part, n, bid, tid,
                 skey, scnt2);
  grid.sync();
  phase_pairs(x, beta, oid, ktab, pairs_part, n, nitems, bid, tid,
              (int)gridDim.x, skt, sred);
  grid.sync();
  if (bid == 0)
    phase_final(pairs_part, (int)gridDim.x, scal_part, cow_part, out, tid, sred);
}

// ======================= standalone fallback kernels =======================
__global__ __launch_bounds__(256) void
k_prep_s(const float* __restrict__ beta, const int* __restrict__ oid,
         const float* __restrict__ energy, const float* __restrict__ eph,
         const float* __restrict__ mom, const float* __restrict__ mph,
         const float* __restrict__ logits, const int* __restrict__ pid,
         unsigned long long* __restrict__ amax_part,
         unsigned* __restrict__ cnt_part, float* __restrict__ scal_part, int n) {
  __shared__ unsigned long long lmax[KOBJ];
  __shared__ unsigned lcnt[KOBJ];
  __shared__ float sred[4][10];
  phase_prep(beta, oid, energy, eph, mom, mph, logits, pid,
             amax_part, cnt_part, scal_part, n, blockIdx.x, threadIdx.x,
             lmax, lcnt, sred);
}

__global__ __launch_bounds__(256) void
k_gather_s(const float* __restrict__ x, const float* __restrict__ beta,
           const unsigned long long* __restrict__ amax_part,
           const unsigned* __restrict__ cnt_part,
           float* __restrict__ ktab, float* __restrict__ cow_part, int n) {
  __shared__ unsigned long long skey[32][8];
  __shared__ unsigned scnt2[32][8];
  phase_gather(x, beta, amax_part, cnt_part, ktab, cow_part, n,
               blockIdx.x, threadIdx.x, skey, scnt2);
}

__global__ __launch_bounds__(256) void
k_pairs_s(const float* __restrict__ x, const float* __restrict__ beta,
          const int* __restrict__ oid, const float* __restrict__ ktab,
          float* __restrict__ pairs_part, int n, int nitems) {
  __shared__ float skt[TK * KTW];
  __shared__ float sred[4][10];
  phase_pairs(x, beta, oid, ktab, pairs_part, n, nitems,
              blockIdx.x, threadIdx.x, (int)gridDim.x, skt, sred);
}

__global__ __launch_bounds__(256) void
k_final_s(const float* __restrict__ pairs_part, int nb_part,
          const float* __restrict__ scal_part,
          const float* __restrict__ cow_part, float* __restrict__ out) {
  __shared__ float sred[4][10];
  phase_final(pairs_part, nb_part, scal_part, cow_part, out,
              threadIdx.x, sred);
}

extern "C" void kernel_launch(void* const* d_in, const int* in_sizes, int n_in,
                              void* d_out, int out_size, void* d_ws, size_t ws_size,
                              hipStream_t stream) {
  const float* beta   = (const float*)d_in[0];
  const float* x      = (const float*)d_in[1];
  const int*   oid    = (const int*)d_in[2];
  const float* energy = (const float*)d_in[3];
  const float* eph    = (const float*)d_in[4];
  const float* mom    = (const float*)d_in[5];
  const float* mph    = (const float*)d_in[6];
  const float* logits = (const float*)d_in[7];
  const int*   pid    = (const int*)d_in[8];
  float* out = (float*)d_out;
  const int n = in_sizes[0];
  const int nhb = (n + HCH - 1) / HCH;      // hit-chunks (118)
  const int nitems = nhb * NTILE;           // pairs items (944)
  const int npart_max = (nitems > GRID) ? nitems : GRID;

  char* base = (char*)d_ws;
  size_t off = 0;
  float* ktab       = (float*)(base + off); off += (size_t)KOBJ * KTW * 4;
  float* cow_part   = (float*)(base + off); off += GGATH * 4;
  float* pairs_part = (float*)(base + off); off += (size_t)npart_max * 4 * 4;
  off = (off + 255) & ~(size_t)255;
  unsigned long long* amax_part = (unsigned long long*)(base + off); off += (size_t)MPREP * KOBJ * 8;
  unsigned* cnt_part = (unsigned*)(base + off);                      off += (size_t)MPREP * KOBJ * 4;
  float* scal_part   = (float*)(base + off);                         off += (size_t)MPREP * 8 * 4;

  int n_arg = n, nitems_arg = nitems;
  void* args[] = {
    (void*)&beta, (void*)&x, (void*)&oid, (void*)&energy, (void*)&eph,
    (void*)&mom, (void*)&mph, (void*)&logits, (void*)&pid,
    (void*)&amax_part, (void*)&cnt_part, (void*)&scal_part,
    (void*)&ktab, (void*)&cow_part, (void*)&pairs_part, (void*)&out,
    (void*)&n_arg, (void*)&nitems_arg
  };
  hipError_t err = hipLaunchCooperativeKernel((const void*)k_fused, dim3(GRID),
                                              dim3(256), args, 0, stream);
  if (err != hipSuccess) {
    // fallback: proven 4-kernel path (identical math via shared phase functions)
    k_prep_s<<<MPREP, 256, 0, stream>>>(beta, oid, energy, eph, mom, mph,
                                        logits, pid, amax_part, cnt_part,
                                        scal_part, n);
    k_gather_s<<<GGATH, 256, 0, stream>>>(x, beta, amax_part, cnt_part,
                                          ktab, cow_part, n);
    k_pairs_s<<<nitems, 256, 0, stream>>>(x, beta, oid, ktab, pairs_part,
                                          n, nitems);
    k_final_s<<<1, 256, 0, stream>>>(pairs_part, nitems, scal_part,
                                     cow_part, out);
  }
}

// Round 7
// 239.426 us; speedup vs baseline: 1.2437x; 1.2437x over previous
//
#include <hip/hip_runtime.h>
#include <math.h>

#define KOBJ 512
#define KTW 12      // packed row: x[8], xk2, w_rep, w_att, pad
#define TK 64       // k-tile per pairs item
#define NTILE (KOBJ / TK)   // 8
#define HB 4        // hits per thread (register blocking)
#define HCH (256 * HB)      // 1024 hits per item
#define MPREP 256   // prep blocks

__device__ __forceinline__ float wave_red_f(float v) {
  #pragma unroll
  for (int off = 32; off > 0; off >>= 1) v += __shfl_down(v, off, 64);
  return v;
}

// fast atanh(b)^2 + 1 ; b in (0, 0.96]
__device__ __forceinline__ float q_of_beta(float b) {
  float a = 0.5f * __logf((1.f + b) / (1.f - b));
  return fmaf(a, a, 1.f);
}

// ---------------------------------------------------------------------------
// k_A: prep (all blocks) + gather (last finishing block).
// Last-block-done via device-scope atomic ticket + threadfence (no grid.sync).
// ---------------------------------------------------------------------------
__global__ __launch_bounds__(256) void
k_A(const float* __restrict__ beta, const float* __restrict__ x,
    const int* __restrict__ oid,
    const float* __restrict__ energy, const float* __restrict__ eph,
    const float* __restrict__ mom, const float* __restrict__ mph,
    const float* __restrict__ logits, const int* __restrict__ pid,
    unsigned long long* __restrict__ amax_part,
    unsigned* __restrict__ cnt_part, float* __restrict__ scal_part,
    float* __restrict__ ktab, float* __restrict__ cow_sum,
    unsigned* __restrict__ ctr, int n) {
  __shared__ unsigned long long lmax[KOBJ];
  __shared__ unsigned lcnt[KOBJ];
  __shared__ float sred[4][6];
  __shared__ int sticket;
  const int tid = threadIdx.x;
  const int bid = blockIdx.x;

  // ---- prep ----
  for (int t = tid; t < KOBJ; t += 256) { lmax[t] = 0ull; lcnt[t] = 0u; }
  __syncthreads();

  float e_t = 0.f, p_t = 0.f, pid_t = 0.f, noise_t = 0.f, ncnt = 0.f, mcnt = 0.f;
  for (int i = bid * 256 + tid; i < n; i += MPREP * 256) {
    float b = beta[i];
    int o = oid[i];
    if (o > 0) {
      float q = q_of_beta(b);
      // pack (q bits | ~i): max-q wins, ties -> smallest index (argmax semantics)
      unsigned long long key = ((unsigned long long)__float_as_uint(q) << 32)
                             | (unsigned long long)(unsigned)(~(unsigned)i);
      atomicMax(&lmax[o - 1], key);
      atomicAdd(&lcnt[o - 1], 1u);
      mcnt += 1.f;
      float de = energy[i] - eph[i];
      e_t = fmaf(de, de, e_t);
      float p0 = mom[3*i+0] - mph[3*i+0];
      float p1 = mom[3*i+1] - mph[3*i+1];
      float p2 = mom[3*i+2] - mph[3*i+2];
      p_t = fmaf(p0, p0, p_t); p_t = fmaf(p1, p1, p_t); p_t = fmaf(p2, p2, p_t);
      const float* lg = logits + 6*i;
      float l0=lg[0], l1=lg[1], l2=lg[2], l3=lg[3], l4=lg[4], l5=lg[5];
      float mx = fmaxf(fmaxf(fmaxf(l0,l1),fmaxf(l2,l3)), fmaxf(l4,l5));
      float s = __expf(l0-mx)+__expf(l1-mx)+__expf(l2-mx)
              + __expf(l3-mx)+__expf(l4-mx)+__expf(l5-mx);
      int pc = pid[i];
      float lp = (pc==0)?l0:(pc==1)?l1:(pc==2)?l2:(pc==3)?l3:(pc==4)?l4:l5;
      pid_t += mx + __logf(s) - lp;
    } else {
      noise_t += b;
      ncnt += 1.f;
    }
  }
  __syncthreads();

  for (int t = tid; t < KOBJ; t += 256) {
    amax_part[(size_t)bid * KOBJ + t] = lmax[t];
    cnt_part[(size_t)bid * KOBJ + t]  = lcnt[t];
  }

  float vals[6] = {e_t, p_t, pid_t, noise_t, ncnt, mcnt};
  #pragma unroll
  for (int j = 0; j < 6; j++) vals[j] = wave_red_f(vals[j]);
  int w = tid >> 6, l = tid & 63;
  if (l == 0) {
    #pragma unroll
    for (int j = 0; j < 6; j++) sred[w][j] = vals[j];
  }
  __syncthreads();
  if (tid == 0) {
    #pragma unroll
    for (int j = 0; j < 6; j++)
      scal_part[bid * 8 + j] = sred[0][j]+sred[1][j]+sred[2][j]+sred[3][j];
  }

  // ---- last-block ticket ----
  __threadfence();                      // release my partials (agent scope)
  if (tid == 0) sticket = (int)atomicAdd(ctr, 1u);
  __syncthreads();
  if (sticket != MPREP - 1) return;

  // ---- gather (single last block) ----
  __threadfence();                      // acquire others' partials
  float cow = 0.f;
  for (int k = tid; k < KOBJ; k += 256) {   // 2 objects per thread
    unsigned long long key = 0ull;
    unsigned cnt = 0u;
    #pragma unroll 8
    for (int m = 0; m < MPREP; m++) {
      unsigned long long km = amax_part[(size_t)m * KOBJ + k];
      key = (km > key) ? km : key;
      cnt += cnt_part[(size_t)m * KOBJ + k];
    }
    unsigned idx = ~(unsigned)(key & 0xffffffffull);
    float q_k = __uint_as_float((unsigned)(key >> 32));
    const float4* xp = (const float4*)x;
    float4 xa = xp[2 * (size_t)idx];
    float4 xb = xp[2 * (size_t)idx + 1];
    float xv[8] = {xa.x, xa.y, xa.z, xa.w, xb.x, xb.y, xb.z, xb.w};
    float s2 = 0.f;
    #pragma unroll
    for (int c = 0; c < 8; c++) s2 = fmaf(xv[c], xv[c], s2);
    float* kt = ktab + (size_t)k * KTW;
    #pragma unroll
    for (int c = 0; c < 8; c++) kt[c] = xv[c];
    kt[8]  = s2;
    kt[9]  = q_k / ((float)(n - (int)cnt) + 1e-9f);   // w_rep
    kt[10] = q_k / ((float)cnt + 1e-9f);              // w_att
    kt[11] = 0.f;
    cow += 1.f - beta[idx];
  }
  cow = wave_red_f(cow);
  __syncthreads();
  if (l == 0) sred[w][0] = cow;
  __syncthreads();
  if (tid == 0)
    cow_sum[0] = sred[0][0]+sred[1][0]+sred[2][0]+sred[3][0];
  // kernel boundary orders ktab/cow_sum for k_B (same stream)
}

// ---------------------------------------------------------------------------
// k_B: pairs (all blocks; round-4 proven hot loop) + finalize (last block).
// ---------------------------------------------------------------------------
__global__ __launch_bounds__(256) void
k_B(const float* __restrict__ x, const float* __restrict__ beta,
    const int* __restrict__ oid, const float* __restrict__ ktab,
    const float* __restrict__ scal_part, const float* __restrict__ cow_sum,
    float* __restrict__ pairs_part, unsigned* __restrict__ ctr,
    float* __restrict__ out, int n, int nblk_tot) {
  __shared__ float skt[TK * KTW];   // 3 KiB
  __shared__ float sred[4][9];
  __shared__ int sticket;
  const int tid = threadIdx.x;
  const int bid = blockIdx.y * gridDim.x + blockIdx.x;
  const int tile0 = blockIdx.y * TK;
  const int hbase = blockIdx.x * HCH;

  for (int t = tid; t < TK * KTW; t += 256)
    skt[t] = ktab[(size_t)tile0 * KTW + t];
  __syncthreads();

  float yi[HB][8], b2[HB], qi[HB];
  int own[HB];
  const float4* xp = (const float4*)x;
  #pragma unroll
  for (int h = 0; h < HB; h++) {
    int i = hbase + h * 256 + tid;
    if (i < n) {
      float4 xa = xp[2 * (size_t)i];
      float4 xb = xp[2 * (size_t)i + 1];
      float xi[8] = {xa.x, xa.y, xa.z, xa.w, xb.x, xb.y, xb.z, xb.w};
      float s = 0.f;
      #pragma unroll
      for (int c = 0; c < 8; c++) {
        s = fmaf(xi[c], xi[c], s);
        yi[h][c] = -2.f * xi[c];
      }
      b2[h] = s;
      qi[h] = q_of_beta(beta[i]);
      own[h] = oid[i] - 1 - tile0;   // own object within tile (or out of range)
    } else {
      #pragma unroll
      for (int c = 0; c < 8; c++) yi[h][c] = 0.f;
      b2[h] = 3.f;                   // d2 = 3 + xk2 >= 3 : never passes hinge
      qi[h] = 0.f;
      own[h] = -1;
    }
  }

  float att = 0.f, rep = 0.f, nrep = 0.f;
  #pragma unroll 2
  for (int k = 0; k < TK; k++) {
    const float* kt = &skt[k * KTW];
    float k0 = kt[0], k1 = kt[1], k2 = kt[2], k3 = kt[3];
    float k4 = kt[4], k5 = kt[5], k6 = kt[6], k7 = kt[7];
    float s2 = kt[8], wr = kt[9];
    #pragma unroll
    for (int h = 0; h < HB; h++) {
      float d2 = b2[h] + s2;
      d2 = fmaf(yi[h][0], k0, d2);
      d2 = fmaf(yi[h][1], k1, d2);
      d2 = fmaf(yi[h][2], k2, d2);
      d2 = fmaf(yi[h][3], k3, d2);
      d2 = fmaf(yi[h][4], k4, d2);
      d2 = fmaf(yi[h][5], k5, d2);
      d2 = fmaf(yi[h][6], k6, d2);
      d2 = fmaf(yi[h][7], k7, d2);
      // dist<1 <=> d2<1 ; sqrt only on the rare accepted pair
      if (d2 < 1.f) {
        float dist = sqrtf(fmaxf(d2, 1e-12f));
        rep = fmaf(qi[h] * (1.f - dist), wr, rep);
        nrep += 1.f;
      }
    }
  }

  // own-object: attractive term + undo in-loop repulsive contribution
  #pragma unroll
  for (int h = 0; h < HB; h++) {
    int ko = own[h];
    if (ko >= 0 && ko < TK) {
      const float* kt = &skt[ko * KTW];
      float d2 = b2[h] + kt[8];
      #pragma unroll
      for (int c = 0; c < 8; c++) d2 = fmaf(yi[h][c], kt[c], d2);
      att = fmaf(qi[h] * fmaxf(d2, 0.f), kt[10], att);
      if (d2 < 1.f) {
        float dist = sqrtf(fmaxf(d2, 1e-12f));
        rep = fmaf(-qi[h] * (1.f - dist), kt[9], rep);
        nrep -= 1.f;
      }
    }
  }

  att = wave_red_f(att);
  rep = wave_red_f(rep);
  nrep = wave_red_f(nrep);
  int w = tid >> 6, l = tid & 63;
  if (l == 0) { sred[w][0] = att; sred[w][1] = rep; sred[w][2] = nrep; }
  __syncthreads();
  if (tid == 0) {
    pairs_part[bid * 4 + 0] = sred[0][0]+sred[1][0]+sred[2][0]+sred[3][0];
    pairs_part[bid * 4 + 1] = sred[0][1]+sred[1][1]+sred[2][1]+sred[3][1];
    pairs_part[bid * 4 + 2] = sred[0][2]+sred[1][2]+sred[2][2]+sred[3][2];
  }

  // ---- last-block ticket ----
  __threadfence();
  if (tid == 0) sticket = (int)atomicAdd(ctr, 1u);
  __syncthreads();
  if (sticket != nblk_tot - 1) return;

  // ---- finalize (single last block) ----
  __threadfence();
  float v[9];
  #pragma unroll
  for (int j = 0; j < 9; j++) v[j] = 0.f;
  // v: att, rep, nrep, e, p, pid, noise, ncnt, mcnt
  for (int b = tid; b < nblk_tot; b += 256) {
    v[0] += pairs_part[b * 4 + 0];
    v[1] += pairs_part[b * 4 + 1];
    v[2] += pairs_part[b * 4 + 2];
  }
  for (int m = tid; m < MPREP; m += 256) {
    #pragma unroll
    for (int j = 0; j < 6; j++) v[3 + j] += scal_part[m * 8 + j];
  }
  #pragma unroll
  for (int j = 0; j < 9; j++) v[j] = wave_red_f(v[j]);
  __syncthreads();
  if (l == 0) {
    #pragma unroll
    for (int j = 0; j < 9; j++) sred[w][j] = v[j];
  }
  __syncthreads();
  if (tid == 0) {
    float t[9];
    #pragma unroll
    for (int j = 0; j < 9; j++) t[j] = sred[0][j]+sred[1][j]+sred[2][j]+sred[3][j];
    float v_att  = t[0] / (float)KOBJ;
    float v_rep  = t[1] / (float)KOBJ;
    float n_rep  = t[2];
    float l_cow  = cow_sum[0] / (float)KOBJ;
    float l_noise = t[6] / t[7];
    float oc = v_att + v_rep + l_cow + l_noise;
    float nm = t[8];
    float e_loss  = t[3] / nm;
    float p_loss  = t[4] / (nm * 3.f);
    float pid_loss = t[5] / nm;
    out[0] = v_att;
    out[1] = v_rep;
    out[2] = l_cow;
    out[3] = l_noise;
    out[4] = n_rep;
    out[5] = oc;
    out[6] = e_loss;
    out[7] = p_loss;
    out[8] = pid_loss;
    out[9] = oc + e_loss + p_loss + pid_loss;
  }
}

extern "C" void kernel_launch(void* const* d_in, const int* in_sizes, int n_in,
                              void* d_out, int out_size, void* d_ws, size_t ws_size,
                              hipStream_t stream) {
  const float* beta   = (const float*)d_in[0];
  const float* x      = (const float*)d_in[1];
  const int*   oid    = (const int*)d_in[2];
  const float* energy = (const float*)d_in[3];
  const float* eph    = (const float*)d_in[4];
  const float* mom    = (const float*)d_in[5];
  const float* mph    = (const float*)d_in[6];
  const float* logits = (const float*)d_in[7];
  const int*   pid    = (const int*)d_in[8];
  float* out = (float*)d_out;
  const int n = in_sizes[0];
  const int nhb = (n + HCH - 1) / HCH;      // hit-chunks (118)
  const int nblk_tot = nhb * NTILE;         // 944

  char* base = (char*)d_ws;
  size_t off = 0;
  unsigned* ctr     = (unsigned*)(base + off); off += 2 * 4;   // [ctrA, ctrB]
  off = (off + 255) & ~(size_t)255;
  float* ktab       = (float*)(base + off); off += (size_t)KOBJ * KTW * 4;
  float* cow_sum    = (float*)(base + off); off += 4 * 4;
  float* pairs_part = (float*)(base + off); off += (size_t)nblk_tot * 4 * 4;
  off = (off + 255) & ~(size_t)255;
  unsigned long long* amax_part = (unsigned long long*)(base + off); off += (size_t)MPREP * KOBJ * 8;
  unsigned* cnt_part = (unsigned*)(base + off);                      off += (size_t)MPREP * KOBJ * 4;
  float* scal_part   = (float*)(base + off);                         off += (size_t)MPREP * 8 * 4;

  hipMemsetAsync(ctr, 0, 2 * 4, stream);   // zero the two tickets (ws is poisoned)
  k_A<<<MPREP, 256, 0, stream>>>(beta, x, oid, energy, eph, mom, mph, logits, pid,
                                 amax_part, cnt_part, scal_part, ktab, cow_sum,
                                 &ctr[0], n);
  k_B<<<dim3(nhb, NTILE), 256, 0, stream>>>(x, beta, oid, ktab, scal_part, cow_sum,
                                            pairs_part, &ctr[1], out, n, nblk_tot);
}

// Round 8
// 164.096 us; speedup vs baseline: 1.8146x; 1.4591x over previous
//
#include <hip/hip_runtime.h>
#include <math.h>

#define KOBJ 512
#define KTW 16      // packed row (64B-aligned): x[8], xk2, w_rep, w_att, pad[5]
#define TK 128      // k-tile per pairs block
#define NTILE (KOBJ / TK)   // 4
#define HB 4        // hits per thread (register blocking)
#define HCH (256 * HB)      // 1024 hits per block
#define MPREP 256   // prep blocks

__device__ __forceinline__ float wave_red_f(float v) {
  #pragma unroll
  for (int off = 32; off > 0; off >>= 1) v += __shfl_down(v, off, 64);
  return v;
}

// fast atanh(b)^2 + 1 ; b in (0, 0.96]
__device__ __forceinline__ float q_of_beta(float b) {
  float a = 0.5f * __logf((1.f + b) / (1.f - b));
  return fmaf(a, a, 1.f);
}

// ---------------------------------------------------------------------------
// Pass 1: 256 blocks. LDS-aggregated per-object argmax(q)/counts flushed as
// per-block partial tables; payload losses reduced per block. No global atomics.
// ---------------------------------------------------------------------------
__global__ __launch_bounds__(256) void
k_prep(const float* __restrict__ beta, const int* __restrict__ oid,
       const float* __restrict__ energy, const float* __restrict__ eph,
       const float* __restrict__ mom, const float* __restrict__ mph,
       const float* __restrict__ logits, const int* __restrict__ pid,
       unsigned long long* __restrict__ amax_part,
       unsigned* __restrict__ cnt_part,
       float* __restrict__ scal_part, int n) {
  __shared__ unsigned long long lmax[KOBJ];
  __shared__ unsigned lcnt[KOBJ];
  for (int t = threadIdx.x; t < KOBJ; t += 256) { lmax[t] = 0ull; lcnt[t] = 0u; }
  __syncthreads();

  float e_t = 0.f, p_t = 0.f, pid_t = 0.f, noise_t = 0.f, ncnt = 0.f, mcnt = 0.f;
  for (int i = blockIdx.x * 256 + threadIdx.x; i < n; i += MPREP * 256) {
    float b = beta[i];
    int o = oid[i];
    if (o > 0) {
      float q = q_of_beta(b);
      // pack (q bits | ~i): max-q wins, ties -> smallest index (argmax semantics)
      unsigned long long key = ((unsigned long long)__float_as_uint(q) << 32)
                             | (unsigned long long)(unsigned)(~(unsigned)i);
      atomicMax(&lmax[o - 1], key);
      atomicAdd(&lcnt[o - 1], 1u);
      mcnt += 1.f;
      float de = energy[i] - eph[i];
      e_t = fmaf(de, de, e_t);
      float p0 = mom[3*i+0] - mph[3*i+0];
      float p1 = mom[3*i+1] - mph[3*i+1];
      float p2 = mom[3*i+2] - mph[3*i+2];
      p_t = fmaf(p0, p0, p_t); p_t = fmaf(p1, p1, p_t); p_t = fmaf(p2, p2, p_t);
      const float* lg = logits + 6*i;
      float l0=lg[0], l1=lg[1], l2=lg[2], l3=lg[3], l4=lg[4], l5=lg[5];
      float mx = fmaxf(fmaxf(fmaxf(l0,l1),fmaxf(l2,l3)), fmaxf(l4,l5));
      float s = __expf(l0-mx)+__expf(l1-mx)+__expf(l2-mx)
              + __expf(l3-mx)+__expf(l4-mx)+__expf(l5-mx);
      int pc = pid[i];
      float lp = (pc==0)?l0:(pc==1)?l1:(pc==2)?l2:(pc==3)?l3:(pc==4)?l4:l5;
      pid_t += mx + __logf(s) - lp;
    } else {
      noise_t += b;
      ncnt += 1.f;
    }
  }
  __syncthreads();

  for (int t = threadIdx.x; t < KOBJ; t += 256) {
    amax_part[(size_t)blockIdx.x * KOBJ + t] = lmax[t];
    cnt_part[(size_t)blockIdx.x * KOBJ + t]  = lcnt[t];
  }

  float vals[6] = {e_t, p_t, pid_t, noise_t, ncnt, mcnt};
  #pragma unroll
  for (int j = 0; j < 6; j++) vals[j] = wave_red_f(vals[j]);
  __shared__ float sred[4][6];
  int w = threadIdx.x >> 6, l = threadIdx.x & 63;
  if (l == 0) {
    #pragma unroll
    for (int j = 0; j < 6; j++) sred[w][j] = vals[j];
  }
  __syncthreads();
  if (threadIdx.x == 0) {
    #pragma unroll
    for (int j = 0; j < 6; j++)
      scal_part[blockIdx.x * 8 + j] = sred[0][j]+sred[1][j]+sred[2][j]+sred[3][j];
  }
}

// ---------------------------------------------------------------------------
// Pass 2: 8 blocks x 256 threads. Block b owns objects [b*64,(b+1)*64);
// thread = (m_chunk 0..3, object). Reduce 256 partials, decode condensation
// point, emit packed 16-float row + per-block coward partial.
// ---------------------------------------------------------------------------
__global__ __launch_bounds__(256) void
k_gather(const float* __restrict__ x, const float* __restrict__ beta,
         const unsigned long long* __restrict__ amax_part,
         const unsigned* __restrict__ cnt_part,
         float* __restrict__ ktab, float* __restrict__ cow_part, int n) {
  int ko = threadIdx.x & 63;          // object within block
  int chunk = threadIdx.x >> 6;       // 0..3 m-chunk
  int k = blockIdx.x * 64 + ko;       // global object id - 1
  const int mpc = MPREP / 4;          // 64
  int m0 = chunk * mpc, m1 = m0 + mpc;

  unsigned long long key = 0ull;
  unsigned cnt = 0u;
  for (int m = m0; m < m1; m++) {
    unsigned long long km = amax_part[(size_t)m * KOBJ + k];
    key = (km > key) ? km : key;
    cnt += cnt_part[(size_t)m * KOBJ + k];
  }
  __shared__ unsigned long long skey[4][64];
  __shared__ unsigned scnt[4][64];
  skey[chunk][ko] = key;
  scnt[chunk][ko] = cnt;
  __syncthreads();

  float cow = 0.f;
  if (chunk == 0) {
    #pragma unroll
    for (int c = 1; c < 4; c++) {
      unsigned long long kc = skey[c][ko];
      key = (kc > key) ? kc : key;
      cnt += scnt[c][ko];
    }
    unsigned idx = ~(unsigned)(key & 0xffffffffull);
    float q_k = __uint_as_float((unsigned)(key >> 32));
    const float4* xp = (const float4*)x;
    float4 xa = xp[2 * (size_t)idx];
    float4 xb = xp[2 * (size_t)idx + 1];
    float xv[8] = {xa.x, xa.y, xa.z, xa.w, xb.x, xb.y, xb.z, xb.w};
    float s2 = 0.f;
    #pragma unroll
    for (int c = 0; c < 8; c++) s2 = fmaf(xv[c], xv[c], s2);
    float* kt = ktab + (size_t)k * KTW;
    #pragma unroll
    for (int c = 0; c < 8; c++) kt[c] = xv[c];
    kt[8]  = s2;
    kt[9]  = q_k / ((float)(n - (int)cnt) + 1e-9f);   // w_rep
    kt[10] = q_k / ((float)cnt + 1e-9f);              // w_att
    kt[11] = 0.f; kt[12] = 0.f; kt[13] = 0.f; kt[14] = 0.f; kt[15] = 0.f;
    cow = 1.f - beta[idx];
    cow = wave_red_f(cow);   // chunk==0 threads are exactly wave 0
    if (ko == 0) cow_part[blockIdx.x] = cow;
  }
}

// ---------------------------------------------------------------------------
// Pass 3 (hot): 2D grid (118 hit-blocks x 4 k-tiles). Each thread holds HB=4
// hits in registers; the k-loop reads the object row at a WAVE-UNIFORM
// address directly from global -> compiler emits s_load (SGPR broadcast,
// constant-cache resident, separate SMEM pipe). No LDS, no barriers in the
// hot loop. Own-object term subtracted after the loop.
// ---------------------------------------------------------------------------
__global__ __launch_bounds__(256, 4) void
k_pairs(const float* __restrict__ x, const float* __restrict__ beta,
        const int* __restrict__ oid, const float* __restrict__ ktab,
        float* __restrict__ pairs_part, int n) {
  const int tid = threadIdx.x;
  const int tile0 = blockIdx.y * TK;
  const int hbase = blockIdx.x * HCH;

  // load HB hits into registers
  float yi[HB][8], b2[HB], qi[HB];
  int own[HB];
  const float4* xp = (const float4*)x;
  #pragma unroll
  for (int h = 0; h < HB; h++) {
    int i = hbase + h * 256 + tid;
    if (i < n) {
      float4 xa = xp[2 * (size_t)i];
      float4 xb = xp[2 * (size_t)i + 1];
      float xi[8] = {xa.x, xa.y, xa.z, xa.w, xb.x, xb.y, xb.z, xb.w};
      float s = 0.f;
      #pragma unroll
      for (int c = 0; c < 8; c++) {
        s = fmaf(xi[c], xi[c], s);
        yi[h][c] = -2.f * xi[c];
      }
      b2[h] = s;
      qi[h] = q_of_beta(beta[i]);
      own[h] = oid[i] - 1 - tile0;   // own object within tile (or out of range)
    } else {
      #pragma unroll
      for (int c = 0; c < 8; c++) yi[h][c] = 0.f;
      b2[h] = 3.f;                   // d2 = 3 + xk2 >= 3 : never passes hinge
      qi[h] = 0.f;
      own[h] = -1;
    }
  }

  float att = 0.f, rep = 0.f, nrep = 0.f;
  const float* __restrict__ ktb = ktab + (size_t)tile0 * KTW;
  #pragma unroll 4
  for (int k = 0; k < TK; k++) {
    const float* kt = ktb + k * KTW;   // wave-uniform address -> s_load
    float k0 = kt[0], k1 = kt[1], k2 = kt[2], k3 = kt[3];
    float k4 = kt[4], k5 = kt[5], k6 = kt[6], k7 = kt[7];
    float s2 = kt[8], wr = kt[9];
    #pragma unroll
    for (int h = 0; h < HB; h++) {
      float d2 = b2[h] + s2;
      d2 = fmaf(yi[h][0], k0, d2);
      d2 = fmaf(yi[h][1], k1, d2);
      d2 = fmaf(yi[h][2], k2, d2);
      d2 = fmaf(yi[h][3], k3, d2);
      d2 = fmaf(yi[h][4], k4, d2);
      d2 = fmaf(yi[h][5], k5, d2);
      d2 = fmaf(yi[h][6], k6, d2);
      d2 = fmaf(yi[h][7], k7, d2);
      // dist<1 <=> d2<1 ; sqrt only on the rare accepted pair
      if (d2 < 1.f) {
        float dist = sqrtf(fmaxf(d2, 1e-12f));
        rep = fmaf(qi[h] * (1.f - dist), wr, rep);
        nrep += 1.f;
      }
    }
  }

  // own-object: attractive term + undo in-loop repulsive contribution
  #pragma unroll
  for (int h = 0; h < HB; h++) {
    int ko = own[h];
    if (ko >= 0 && ko < TK) {
      const float* kt = ktb + ko * KTW;   // divergent but rare: vector load path
      float d2 = b2[h] + kt[8];
      #pragma unroll
      for (int c = 0; c < 8; c++) d2 = fmaf(yi[h][c], kt[c], d2);
      att = fmaf(qi[h] * fmaxf(d2, 0.f), kt[10], att);
      if (d2 < 1.f) {
        float dist = sqrtf(fmaxf(d2, 1e-12f));
        rep = fmaf(-qi[h] * (1.f - dist), kt[9], rep);
        nrep -= 1.f;
      }
    }
  }

  att = wave_red_f(att);
  rep = wave_red_f(rep);
  nrep = wave_red_f(nrep);
  __shared__ float sred[4][3];
  int w = tid >> 6, l = tid & 63;
  if (l == 0) { sred[w][0] = att; sred[w][1] = rep; sred[w][2] = nrep; }
  __syncthreads();
  if (tid == 0) {
    int bid = blockIdx.y * gridDim.x + blockIdx.x;
    pairs_part[bid * 4 + 0] = sred[0][0]+sred[1][0]+sred[2][0]+sred[3][0];
    pairs_part[bid * 4 + 1] = sred[0][1]+sred[1][1]+sred[2][1]+sred[3][1];
    pairs_part[bid * 4 + 2] = sred[0][2]+sred[1][2]+sred[2][2]+sred[3][2];
  }
}

// ---------------------------------------------------------------------------
// Pass 4: combine everything.
// ---------------------------------------------------------------------------
__global__ __launch_bounds__(256) void
k_finalize(const float* __restrict__ pairs_part, int nblk_tot,
           const float* __restrict__ scal_part,
           const float* __restrict__ cow_part, float* __restrict__ out) {
  float v[9] = {0,0,0,0,0,0,0,0,0};  // att, rep, nrep, e, p, pid, noise, ncnt, mcnt
  for (int b = threadIdx.x; b < nblk_tot; b += 256) {
    v[0] += pairs_part[b * 4 + 0];
    v[1] += pairs_part[b * 4 + 1];
    v[2] += pairs_part[b * 4 + 2];
  }
  for (int m = threadIdx.x; m < MPREP; m += 256) {
    #pragma unroll
    for (int j = 0; j < 6; j++) v[3 + j] += scal_part[m * 8 + j];
  }
  #pragma unroll
  for (int j = 0; j < 9; j++) v[j] = wave_red_f(v[j]);
  __shared__ float sred[4][9];
  int w = threadIdx.x >> 6, l = threadIdx.x & 63;
  if (l == 0) {
    #pragma unroll
    for (int j = 0; j < 9; j++) sred[w][j] = v[j];
  }
  __syncthreads();
  if (threadIdx.x == 0) {
    float t[9];
    #pragma unroll
    for (int j = 0; j < 9; j++) t[j] = sred[0][j]+sred[1][j]+sred[2][j]+sred[3][j];
    float cow = cow_part[0]+cow_part[1]+cow_part[2]+cow_part[3]
              + cow_part[4]+cow_part[5]+cow_part[6]+cow_part[7];
    float v_att  = t[0] / (float)KOBJ;
    float v_rep  = t[1] / (float)KOBJ;
    float n_rep  = t[2];
    float l_cow  = cow / (float)KOBJ;
    float l_noise = t[6] / t[7];
    float oc = v_att + v_rep + l_cow + l_noise;
    float nm = t[8];
    float e_loss  = t[3] / nm;
    float p_loss  = t[4] / (nm * 3.f);
    float pid_loss = t[5] / nm;
    out[0] = v_att;
    out[1] = v_rep;
    out[2] = l_cow;
    out[3] = l_noise;
    out[4] = n_rep;
    out[5] = oc;
    out[6] = e_loss;
    out[7] = p_loss;
    out[8] = pid_loss;
    out[9] = oc + e_loss + p_loss + pid_loss;
  }
}

extern "C" void kernel_launch(void* const* d_in, const int* in_sizes, int n_in,
                              void* d_out, int out_size, void* d_ws, size_t ws_size,
                              hipStream_t stream) {
  const float* beta   = (const float*)d_in[0];
  const float* x      = (const float*)d_in[1];
  const int*   oid    = (const int*)d_in[2];
  const float* energy = (const float*)d_in[3];
  const float* eph    = (const float*)d_in[4];
  const float* mom    = (const float*)d_in[5];
  const float* mph    = (const float*)d_in[6];
  const float* logits = (const float*)d_in[7];
  const int*   pid    = (const int*)d_in[8];
  float* out = (float*)d_out;
  const int n = in_sizes[0];
  const int nhb = (n + HCH - 1) / HCH;      // hit-chunks (118)
  const int nblk_tot = nhb * NTILE;         // 472

  char* base = (char*)d_ws;
  size_t off = 0;
  float* ktab       = (float*)(base + off); off += (size_t)KOBJ * KTW * 4;
  float* cow_part   = (float*)(base + off); off += 8 * 4;
  float* pairs_part = (float*)(base + off); off += (size_t)nblk_tot * 4 * 4;
  off = (off + 255) & ~(size_t)255;
  unsigned long long* amax_part = (unsigned long long*)(base + off); off += (size_t)MPREP * KOBJ * 8;
  unsigned* cnt_part = (unsigned*)(base + off);                      off += (size_t)MPREP * KOBJ * 4;
  float* scal_part   = (float*)(base + off);                         off += (size_t)MPREP * 8 * 4;

  k_prep<<<MPREP, 256, 0, stream>>>(beta, oid, energy, eph, mom, mph, logits, pid,
                                    amax_part, cnt_part, scal_part, n);
  k_gather<<<8, 256, 0, stream>>>(x, beta, amax_part, cnt_part, ktab, cow_part, n);
  k_pairs<<<dim3(nhb, NTILE), 256, 0, stream>>>(x, beta, oid, ktab, pairs_part, n);
  k_finalize<<<1, 256, 0, stream>>>(pairs_part, nblk_tot, scal_part, cow_part, out);
}

// Round 9
// 114.766 us; speedup vs baseline: 2.5946x; 1.4298x over previous
//
#include <hip/hip_runtime.h>
#include <math.h>

#define KOBJ 512
#define KTW 8       // packed row (32 B): xh[4] (8 fp16), s2, w_rep, w_att, pad
#define TK 64       // k-tile per pairs block
#define NTILE (KOBJ / TK)   // 8
#define HB 4        // hits per thread (register blocking)
#define HCH (256 * HB)      // 1024 hits per block
#define MPREP 512   // prep blocks (<=1 hit/thread at N=120000)
#define GGATH 16    // gather blocks (32 objects each)

typedef _Float16 half2_t __attribute__((ext_vector_type(2)));

__device__ __forceinline__ float wave_red_f(float v) {
  #pragma unroll
  for (int off = 32; off > 0; off >>= 1) v += __shfl_down(v, off, 64);
  return v;
}

// fast atanh(b)^2 + 1 ; b in (0, 0.96]
__device__ __forceinline__ float q_of_beta(float b) {
  float a = 0.5f * __logf((1.f + b) / (1.f - b));
  return fmaf(a, a, 1.f);
}

// acc + y.h0*k.h0 + ... over 8 fp16 components, fp32 accumulate.
// Fixed op order -> bit-identical between in-loop and own-undo paths.
__device__ __forceinline__ float dot8h(uint4 kx, const uint* y, float acc) {
#if __has_builtin(__builtin_amdgcn_fdot2)
  acc = __builtin_amdgcn_fdot2(__builtin_bit_cast(half2_t, y[0]),
                               __builtin_bit_cast(half2_t, kx.x), acc, false);
  acc = __builtin_amdgcn_fdot2(__builtin_bit_cast(half2_t, y[1]),
                               __builtin_bit_cast(half2_t, kx.y), acc, false);
  acc = __builtin_amdgcn_fdot2(__builtin_bit_cast(half2_t, y[2]),
                               __builtin_bit_cast(half2_t, kx.z), acc, false);
  acc = __builtin_amdgcn_fdot2(__builtin_bit_cast(half2_t, y[3]),
                               __builtin_bit_cast(half2_t, kx.w), acc, false);
#else
  const uint kk[4] = {kx.x, kx.y, kx.z, kx.w};
  #pragma unroll
  for (int c = 0; c < 4; c++) {
    half2_t a = __builtin_bit_cast(half2_t, y[c]);
    half2_t b = __builtin_bit_cast(half2_t, kk[c]);
    acc = fmaf((float)a.x, (float)b.x, acc);
    acc = fmaf((float)a.y, (float)b.y, acc);
  }
#endif
  return acc;
}

// ---------------------------------------------------------------------------
// Pass 1: 512 blocks, <=1 hit/thread. LDS-aggregated per-object argmax(q) /
// counts flushed as per-block partial tables; payload losses block-reduced.
// ---------------------------------------------------------------------------
__global__ __launch_bounds__(256) void
k_prep(const float* __restrict__ beta, const int* __restrict__ oid,
       const float* __restrict__ energy, const float* __restrict__ eph,
       const float* __restrict__ mom, const float* __restrict__ mph,
       const float* __restrict__ logits, const int* __restrict__ pid,
       unsigned long long* __restrict__ amax_part,
       unsigned* __restrict__ cnt_part,
       float* __restrict__ scal_part, int n) {
  __shared__ unsigned long long lmax[KOBJ];
  __shared__ unsigned lcnt[KOBJ];
  for (int t = threadIdx.x; t < KOBJ; t += 256) { lmax[t] = 0ull; lcnt[t] = 0u; }
  __syncthreads();

  float e_t = 0.f, p_t = 0.f, pid_t = 0.f, noise_t = 0.f, ncnt = 0.f, mcnt = 0.f;
  for (int i = blockIdx.x * 256 + threadIdx.x; i < n; i += MPREP * 256) {
    float b = beta[i];
    int o = oid[i];
    if (o > 0) {
      float q = q_of_beta(b);
      // pack (q bits | ~i): max-q wins, ties -> smallest index (argmax semantics)
      unsigned long long key = ((unsigned long long)__float_as_uint(q) << 32)
                             | (unsigned long long)(unsigned)(~(unsigned)i);
      atomicMax(&lmax[o - 1], key);
      atomicAdd(&lcnt[o - 1], 1u);
      mcnt += 1.f;
      float de = energy[i] - eph[i];
      e_t = fmaf(de, de, e_t);
      float p0 = mom[3*i+0] - mph[3*i+0];
      float p1 = mom[3*i+1] - mph[3*i+1];
      float p2 = mom[3*i+2] - mph[3*i+2];
      p_t = fmaf(p0, p0, p_t); p_t = fmaf(p1, p1, p_t); p_t = fmaf(p2, p2, p_t);
      const float* lg = logits + 6*i;
      float l0=lg[0], l1=lg[1], l2=lg[2], l3=lg[3], l4=lg[4], l5=lg[5];
      float mx = fmaxf(fmaxf(fmaxf(l0,l1),fmaxf(l2,l3)), fmaxf(l4,l5));
      float s = __expf(l0-mx)+__expf(l1-mx)+__expf(l2-mx)
              + __expf(l3-mx)+__expf(l4-mx)+__expf(l5-mx);
      int pc = pid[i];
      float lp = (pc==0)?l0:(pc==1)?l1:(pc==2)?l2:(pc==3)?l3:(pc==4)?l4:l5;
      pid_t += mx + __logf(s) - lp;
    } else {
      noise_t += b;
      ncnt += 1.f;
    }
  }
  __syncthreads();

  for (int t = threadIdx.x; t < KOBJ; t += 256) {
    amax_part[(size_t)blockIdx.x * KOBJ + t] = lmax[t];
    cnt_part[(size_t)blockIdx.x * KOBJ + t]  = lcnt[t];
  }

  float vals[6] = {e_t, p_t, pid_t, noise_t, ncnt, mcnt};
  #pragma unroll
  for (int j = 0; j < 6; j++) vals[j] = wave_red_f(vals[j]);
  __shared__ float sred[4][6];
  int w = threadIdx.x >> 6, l = threadIdx.x & 63;
  if (l == 0) {
    #pragma unroll
    for (int j = 0; j < 6; j++) sred[w][j] = vals[j];
  }
  __syncthreads();
  if (threadIdx.x == 0) {
    #pragma unroll
    for (int j = 0; j < 6; j++)
      scal_part[blockIdx.x * 8 + j] = sred[0][j]+sred[1][j]+sred[2][j]+sred[3][j];
  }
}

// ---------------------------------------------------------------------------
// Pass 2: 16 blocks x 256 threads. Block b owns objects [b*32,(b+1)*32);
// thread = (m_chunk 0..7, object 0..31). Reduce 512 partials, decode the
// condensation point, emit packed fp16 row + per-block coward partial.
// ---------------------------------------------------------------------------
__global__ __launch_bounds__(256) void
k_gather(const float* __restrict__ x, const float* __restrict__ beta,
         const unsigned long long* __restrict__ amax_part,
         const unsigned* __restrict__ cnt_part,
         uint* __restrict__ ktab, float* __restrict__ cow_part, int n) {
  int ko = threadIdx.x & 31;          // object within block
  int chunk = threadIdx.x >> 5;       // 0..7 m-chunk
  int k = blockIdx.x * 32 + ko;       // global object id - 1
  const int mpc = MPREP / 8;          // 64
  int m0 = chunk * mpc, m1 = m0 + mpc;

  unsigned long long key = 0ull;
  unsigned cnt = 0u;
  for (int m = m0; m < m1; m++) {
    unsigned long long km = amax_part[(size_t)m * KOBJ + k];
    key = (km > key) ? km : key;
    cnt += cnt_part[(size_t)m * KOBJ + k];
  }
  __shared__ unsigned long long skey[8][32];
  __shared__ unsigned scnt[8][32];
  skey[chunk][ko] = key;
  scnt[chunk][ko] = cnt;
  __syncthreads();

  float cow = 0.f;
  if (chunk == 0) {
    #pragma unroll
    for (int c = 1; c < 8; c++) {
      unsigned long long kc = skey[c][ko];
      key = (kc > key) ? kc : key;
      cnt += scnt[c][ko];
    }
    unsigned idx = ~(unsigned)(key & 0xffffffffull);
    float q_k = __uint_as_float((unsigned)(key >> 32));
    const float4* xp = (const float4*)x;
    float4 xa = xp[2 * (size_t)idx];
    float4 xb = xp[2 * (size_t)idx + 1];
    float xv[8] = {xa.x, xa.y, xa.z, xa.w, xb.x, xb.y, xb.z, xb.w};
    float s2 = 0.f;
    #pragma unroll
    for (int c = 0; c < 8; c++) s2 = fmaf(xv[c], xv[c], s2);
    uint* kt = ktab + (size_t)k * KTW;
    #pragma unroll
    for (int c = 0; c < 4; c++) {
      half2_t hp = { (_Float16)xv[2*c], (_Float16)xv[2*c+1] };
      kt[c] = __builtin_bit_cast(uint, hp);
    }
    kt[4] = __float_as_uint(s2);
    kt[5] = __float_as_uint(q_k / ((float)(n - (int)cnt) + 1e-9f));  // w_rep
    kt[6] = __float_as_uint(q_k / ((float)cnt + 1e-9f));             // w_att
    kt[7] = 0u;
    cow = 1.f - beta[idx];
  }
  cow = wave_red_f(cow);   // chunks 1 (lanes 32..63) contribute 0
  if (threadIdx.x == 0) cow_part[blockIdx.x] = cow;
}

// ---------------------------------------------------------------------------
// Pass 3 (hot): 2D grid (118 hit-blocks x 8 k-tiles). HB=4 hits/thread in
// registers (fp16 packed y = -2x); per k: one b128 LDS broadcast row read,
// then per hit 4 v_dot2_f32_f16 + 1 cmp (hinge folded into thr[h] = 1-|xi|^2).
// sqrt only on accepted pairs. Own-object term undone bit-exactly after loop.
// ---------------------------------------------------------------------------
__global__ __launch_bounds__(256, 4) void
k_pairs(const float* __restrict__ x, const float* __restrict__ beta,
        const int* __restrict__ oid, const uint* __restrict__ ktab,
        float* __restrict__ pairs_part, int n) {
  __shared__ __align__(16) uint skt[TK * KTW];   // 2 KiB
  const int tid = threadIdx.x;
  const int tile0 = blockIdx.y * TK;
  const int hbase = blockIdx.x * HCH;

  for (int t = tid; t < TK * KTW; t += 256)
    skt[t] = ktab[(size_t)tile0 * KTW + t];
  __syncthreads();

  // load HB hits into registers
  uint yh[HB][4];
  float thr[HB], bh[HB], qi[HB];
  int own[HB];
  const float4* xp = (const float4*)x;
  #pragma unroll
  for (int h = 0; h < HB; h++) {
    int i = hbase + h * 256 + tid;
    if (i < n) {
      float4 xa = xp[2 * (size_t)i];
      float4 xb = xp[2 * (size_t)i + 1];
      float xi[8] = {xa.x, xa.y, xa.z, xa.w, xb.x, xb.y, xb.z, xb.w};
      float s = 0.f;
      #pragma unroll
      for (int c = 0; c < 8; c++) s = fmaf(xi[c], xi[c], s);
      bh[h] = s;
      thr[h] = 1.f - s;     // accept iff d2' < thr  (d2 = d2' + |xi|^2 < 1)
      #pragma unroll
      for (int c = 0; c < 4; c++) {
        half2_t hy = { (_Float16)(-2.f * xi[2*c]), (_Float16)(-2.f * xi[2*c+1]) };
        yh[h][c] = __builtin_bit_cast(uint, hy);
      }
      qi[h] = q_of_beta(beta[i]);
      own[h] = oid[i] - 1 - tile0;   // own object within tile (or out of range)
    } else {
      #pragma unroll
      for (int c = 0; c < 4; c++) yh[h][c] = 0u;
      bh[h] = 0.f;
      thr[h] = -1e30f;               // never accept
      qi[h] = 0.f;
      own[h] = -1;
    }
  }

  float att = 0.f, rep = 0.f, nrep = 0.f;
  #pragma unroll 2
  for (int k = 0; k < TK; k++) {
    const uint* kr = &skt[k * KTW];
    uint4 kx = *(const uint4*)kr;            // ds_read_b128, wave-uniform
    float s2 = __uint_as_float(kr[4]);
    float wr = __uint_as_float(kr[5]);
    #pragma unroll
    for (int h = 0; h < HB; h++) {
      float dp = dot8h(kx, yh[h], s2);       // s2 - 2*xi.xk (fp16 in, fp32 acc)
      if (dp < thr[h]) {                     // d2 < 1
        float d2 = dp + bh[h];
        float dist = sqrtf(fmaxf(d2, 1e-12f));
        rep = fmaf(qi[h] * (1.f - dist), wr, rep);
        nrep += 1.f;
      }
    }
  }

  // own-object: attractive term + bit-exact undo of in-loop repulsive term
  #pragma unroll
  for (int h = 0; h < HB; h++) {
    int ko = own[h];
    if (ko >= 0 && ko < TK) {
      const uint* kr = &skt[ko * KTW];
      uint4 kx = *(const uint4*)kr;
      float s2 = __uint_as_float(kr[4]);
      float wr = __uint_as_float(kr[5]);
      float wa = __uint_as_float(kr[6]);
      float dp = dot8h(kx, yh[h], s2);       // identical op order -> same bits
      float d2 = dp + bh[h];
      att = fmaf(qi[h] * fmaxf(d2, 0.f), wa, att);
      if (dp < thr[h]) {
        float dist = sqrtf(fmaxf(d2, 1e-12f));
        rep = fmaf(-qi[h] * (1.f - dist), wr, rep);
        nrep -= 1.f;
      }
    }
  }

  att = wave_red_f(att);
  rep = wave_red_f(rep);
  nrep = wave_red_f(nrep);
  __shared__ float sred[4][3];
  int w = tid >> 6, l = tid & 63;
  if (l == 0) { sred[w][0] = att; sred[w][1] = rep; sred[w][2] = nrep; }
  __syncthreads();
  if (tid == 0) {
    int bid = blockIdx.y * gridDim.x + blockIdx.x;
    pairs_part[bid * 4 + 0] = sred[0][0]+sred[1][0]+sred[2][0]+sred[3][0];
    pairs_part[bid * 4 + 1] = sred[0][1]+sred[1][1]+sred[2][1]+sred[3][1];
    pairs_part[bid * 4 + 2] = sred[0][2]+sred[1][2]+sred[2][2]+sred[3][2];
  }
}

// ---------------------------------------------------------------------------
// Pass 4: combine everything.
// ---------------------------------------------------------------------------
__global__ __launch_bounds__(256) void
k_finalize(const float* __restrict__ pairs_part, int nblk_tot,
           const float* __restrict__ scal_part,
           const float* __restrict__ cow_part, float* __restrict__ out) {
  float v[9] = {0,0,0,0,0,0,0,0,0};  // att, rep, nrep, e, p, pid, noise, ncnt, mcnt
  for (int b = threadIdx.x; b < nblk_tot; b += 256) {
    v[0] += pairs_part[b * 4 + 0];
    v[1] += pairs_part[b * 4 + 1];
    v[2] += pairs_part[b * 4 + 2];
  }
  for (int m = threadIdx.x; m < MPREP; m += 256) {
    #pragma unroll
    for (int j = 0; j < 6; j++) v[3 + j] += scal_part[m * 8 + j];
  }
  #pragma unroll
  for (int j = 0; j < 9; j++) v[j] = wave_red_f(v[j]);
  __shared__ float sred[4][9];
  int w = threadIdx.x >> 6, l = threadIdx.x & 63;
  if (l == 0) {
    #pragma unroll
    for (int j = 0; j < 9; j++) sred[w][j] = v[j];
  }
  __syncthreads();
  if (threadIdx.x == 0) {
    float t[9];
    #pragma unroll
    for (int j = 0; j < 9; j++) t[j] = sred[0][j]+sred[1][j]+sred[2][j]+sred[3][j];
    float cow = 0.f;
    #pragma unroll
    for (int g = 0; g < GGATH; g++) cow += cow_part[g];
    float v_att  = t[0] / (float)KOBJ;
    float v_rep  = t[1] / (float)KOBJ;
    float n_rep  = t[2];
    float l_cow  = cow / (float)KOBJ;
    float l_noise = t[6] / t[7];
    float oc = v_att + v_rep + l_cow + l_noise;
    float nm = t[8];
    float e_loss  = t[3] / nm;
    float p_loss  = t[4] / (nm * 3.f);
    float pid_loss = t[5] / nm;
    out[0] = v_att;
    out[1] = v_rep;
    out[2] = l_cow;
    out[3] = l_noise;
    out[4] = n_rep;
    out[5] = oc;
    out[6] = e_loss;
    out[7] = p_loss;
    out[8] = pid_loss;
    out[9] = oc + e_loss + p_loss + pid_loss;
  }
}

extern "C" void kernel_launch(void* const* d_in, const int* in_sizes, int n_in,
                              void* d_out, int out_size, void* d_ws, size_t ws_size,
                              hipStream_t stream) {
  const float* beta   = (const float*)d_in[0];
  const float* x      = (const float*)d_in[1];
  const int*   oid    = (const int*)d_in[2];
  const float* energy = (const float*)d_in[3];
  const float* eph    = (const float*)d_in[4];
  const float* mom    = (const float*)d_in[5];
  const float* mph    = (const float*)d_in[6];
  const float* logits = (const float*)d_in[7];
  const int*   pid    = (const int*)d_in[8];
  float* out = (float*)d_out;
  const int n = in_sizes[0];
  const int nhb = (n + HCH - 1) / HCH;      // hit-chunks (118)
  const int nblk_tot = nhb * NTILE;         // 944

  char* base = (char*)d_ws;
  size_t off = 0;
  uint*  ktab       = (uint*)(base + off);  off += (size_t)KOBJ * KTW * 4;
  float* cow_part   = (float*)(base + off); off += GGATH * 4;
  float* pairs_part = (float*)(base + off); off += (size_t)nblk_tot * 4 * 4;
  off = (off + 255) & ~(size_t)255;
  unsigned long long* amax_part = (unsigned long long*)(base + off); off += (size_t)MPREP * KOBJ * 8;
  unsigned* cnt_part = (unsigned*)(base + off);                      off += (size_t)MPREP * KOBJ * 4;
  float* scal_part   = (float*)(base + off);                         off += (size_t)MPREP * 8 * 4;

  k_prep<<<MPREP, 256, 0, stream>>>(beta, oid, energy, eph, mom, mph, logits, pid,
                                    amax_part, cnt_part, scal_part, n);
  k_gather<<<GGATH, 256, 0, stream>>>(x, beta, amax_part, cnt_part, ktab, cow_part, n);
  k_pairs<<<dim3(nhb, NTILE), 256, 0, stream>>>(x, beta, oid, ktab, pairs_part, n);
  k_finalize<<<1, 256, 0, stream>>>(pairs_part, nblk_tot, scal_part, cow_part, out);
}